// Round 3
// baseline (972.464 us; speedup 1.0000x reference)
//
#include <hip/hip_runtime.h>
#include <hip/hip_bf16.h>

// Problem constants
#define Bb 8
#define Tt 4
#define Nn 1024
#define Mm 4096
#define BT 32         // B*T
#define CIN 256
#define CORIG 128
#define CTOT 384      // CIN + CORIG
#define P1 256
#define P2 256
#define EPS_D 1e-8f
#define EPS_BN 1e-5f

// ---------------------------------------------------------------------------
// Kernel 1: transpose weights W[o][k] -> Wt[k][o] (tiny, done every launch)
// ---------------------------------------------------------------------------
__global__ __launch_bounds__(256) void transpose_w_kernel(
    const float* __restrict__ Win, float* __restrict__ Wt, int K, int P)
{
    int i = blockIdx.x * 256 + threadIdx.x;
    if (i < K * P) {
        int o = i / K;
        int k = i - o * K;           // read coalesced along k
        Wt[k * P + o] = Win[i];
    }
}

// ---------------------------------------------------------------------------
// Kernel 2: three_nn — per query point find 3 nearest (squared dist), weights
// grid: (M/256, BT), block 256
// ---------------------------------------------------------------------------
__global__ __launch_bounds__(256) void three_nn_kernel(
    const float* __restrict__ xyzs,   // [BT][N][3]
    const float* __restrict__ oxyzs,  // [BT][M][3]
    int*   __restrict__ idx_out,      // [BT][M][3]
    float* __restrict__ w_out)        // [BT][M][3]
{
    __shared__ float sx[Nn], sy[Nn], sz[Nn];
    int bt = blockIdx.y;
    const float* base = xyzs + (size_t)bt * Nn * 3;
    for (int i = threadIdx.x; i < Nn; i += 256) {
        sx[i] = base[i * 3 + 0];
        sy[i] = base[i * 3 + 1];
        sz[i] = base[i * 3 + 2];
    }
    __syncthreads();

    int m = blockIdx.x * 256 + threadIdx.x;
    size_t q = ((size_t)bt * Mm + m) * 3;
    float qx = oxyzs[q + 0], qy = oxyzs[q + 1], qz = oxyzs[q + 2];

    float d0 = 3.4e38f, d1 = 3.4e38f, d2v = 3.4e38f;
    int   i0 = 0, i1 = 0, i2 = 0;
    #pragma unroll 4
    for (int n = 0; n < Nn; n++) {
        float dx = qx - sx[n], dy = qy - sy[n], dz = qz - sz[n];
        float d = dx * dx + dy * dy + dz * dz;
        bool lt0 = d < d0, lt1 = d < d1, lt2 = d < d2v;
        // branchless 3-deep insertion (strict <  => lower index wins on ties,
        // matching jax.lax.top_k tie-breaking)
        i2  = lt1 ? i1 : (lt2 ? n : i2);
        d2v = lt1 ? d1 : (lt2 ? d : d2v);
        i1  = lt0 ? i0 : (lt1 ? n : i1);
        d1  = lt0 ? d0 : (lt1 ? d : d1);
        i0  = lt0 ? n : i0;
        d0  = lt0 ? d : d0;
    }
    float w0 = 1.0f / (d0 + EPS_D);
    float w1 = 1.0f / (d1 + EPS_D);
    float w2 = 1.0f / (d2v + EPS_D);
    float inv = 1.0f / (w0 + w1 + w2);
    idx_out[q + 0] = i0; idx_out[q + 1] = i1; idx_out[q + 2] = i2;
    w_out[q + 0] = w0 * inv; w_out[q + 1] = w1 * inv; w_out[q + 2] = w2 * inv;
}

// ---------------------------------------------------------------------------
// Kernel 3: interpolate + concat -> X [BT][384][M]
// grid: (384*16, BT), block 256 — blockIdx.x = c*16 + mblk
// ---------------------------------------------------------------------------
__global__ __launch_bounds__(256) void interp_concat_kernel(
    const float* __restrict__ feats,   // [BT][CIN][N]
    const float* __restrict__ ofeats,  // [BT][CORIG][M]
    const int*   __restrict__ idx,     // [BT][M][3]
    const float* __restrict__ w,       // [BT][M][3]
    float* __restrict__ X)             // [BT][CTOT][M]
{
    int bt = blockIdx.y;
    int c  = blockIdx.x >> 4;
    int m  = ((blockIdx.x & 15) << 8) | threadIdx.x;
    size_t xoff = ((size_t)bt * CTOT + c) * Mm + m;
    if (c < CIN) {
        size_t iw = ((size_t)bt * Mm + m) * 3;
        int   j0 = idx[iw + 0], j1 = idx[iw + 1], j2 = idx[iw + 2];
        float w0 = w[iw + 0],   w1 = w[iw + 1],   w2 = w[iw + 2];
        const float* frow = feats + ((size_t)bt * CIN + c) * Nn;
        X[xoff] = w0 * frow[j0] + w1 * frow[j1] + w2 * frow[j2];
    } else {
        X[xoff] = ofeats[((size_t)bt * CORIG + (c - CIN)) * Mm + m];
    }
}

// ---------------------------------------------------------------------------
// Kernel 4: fp32 tiled GEMM  Y[bt][o][m] = sum_c Wt[c][o] * f(X[bt][c][m])
// f = identity (GEMM1) or BN1+relu (GEMM2 input transform).
// 128x128 tile, BK=8, 256 threads, 8x8 micro-tile.
// Global->reg prefetch pipelining: next k-tile's loads issue right after the
// first barrier so HBM/L2 latency hides under the 8x64-FMA compute block.
// grid: (M/128, P/128, BT)
// ---------------------------------------------------------------------------
template <int KTOT, bool TRANSFORM>
__global__ __launch_bounds__(256) void gemm_kernel(
    const float* __restrict__ Wt,     // [KTOT][256]
    const float* __restrict__ Xg,     // [BT][KTOT][M]
    const float* __restrict__ stats,  // [T][KTOT][2] (a, b) or nullptr
    float* __restrict__ Y)            // [BT][256][M]
{
    int bt = blockIdx.z;
    int t  = bt & (Tt - 1);
    int m0 = blockIdx.x * 128;
    int o0 = blockIdx.y * 128;
    __shared__ float sA[8][128];
    __shared__ float sB[8][128];
    int tid = threadIdx.x;
    int tx = tid & 15, ty = tid >> 4;
    float acc[8][8] = {};
    const float* Xbt = Xg + (size_t)bt * KTOT * Mm;
    int lc = tid >> 5;          // 0..7
    int lr = (tid & 31) * 4;    // 0..124

    // prologue: load k-tile 0 into registers
    float4 av = *(const float4*)&Wt[lc * 256 + o0 + lr];
    float4 bv = *(const float4*)&Xbt[(size_t)lc * Mm + m0 + lr];

    for (int k0 = 0; k0 < KTOT; k0 += 8) {
        if (TRANSFORM) {
            float a = stats[(t * KTOT + k0 + lc) * 2 + 0];
            float b = stats[(t * KTOT + k0 + lc) * 2 + 1];
            bv.x = fmaxf(fmaf(a, bv.x, b), 0.0f);
            bv.y = fmaxf(fmaf(a, bv.y, b), 0.0f);
            bv.z = fmaxf(fmaf(a, bv.z, b), 0.0f);
            bv.w = fmaxf(fmaf(a, bv.w, b), 0.0f);
        }
        *(float4*)&sA[lc][lr] = av;
        *(float4*)&sB[lc][lr] = bv;
        __syncthreads();
        if (k0 + 8 < KTOT) {   // prefetch next k-tile while computing this one
            av = *(const float4*)&Wt[(k0 + 8 + lc) * 256 + o0 + lr];
            bv = *(const float4*)&Xbt[(size_t)(k0 + 8 + lc) * Mm + m0 + lr];
        }
        #pragma unroll
        for (int k = 0; k < 8; k++) {
            float4 a0 = *(float4*)&sA[k][ty * 4];
            float4 a1 = *(float4*)&sA[k][ty * 4 + 64];
            float4 b0 = *(float4*)&sB[k][tx * 4];
            float4 b1 = *(float4*)&sB[k][tx * 4 + 64];
            float ar[8] = {a0.x, a0.y, a0.z, a0.w, a1.x, a1.y, a1.z, a1.w};
            float br[8] = {b0.x, b0.y, b0.z, b0.w, b1.x, b1.y, b1.z, b1.w};
            #pragma unroll
            for (int i = 0; i < 8; i++)
                #pragma unroll
                for (int j = 0; j < 8; j++)
                    acc[i][j] = fmaf(ar[i], br[j], acc[i][j]);
        }
        __syncthreads();
    }

    float* Ybt = Y + (size_t)bt * 256 * Mm;
    #pragma unroll
    for (int i = 0; i < 8; i++) {
        int o = o0 + ((i < 4) ? (ty * 4 + i) : (64 + ty * 4 + i - 4));
        float4 v0 = make_float4(acc[i][0], acc[i][1], acc[i][2], acc[i][3]);
        float4 v1 = make_float4(acc[i][4], acc[i][5], acc[i][6], acc[i][7]);
        *(float4*)&Ybt[(size_t)o * Mm + m0 + tx * 4] = v0;
        *(float4*)&Ybt[(size_t)o * Mm + m0 + 64 + tx * 4] = v1;
    }
}

// ---------------------------------------------------------------------------
// Kernel 5: BN stats per (t,o) over (B, M): emit a = gamma*rsqrt(var+eps),
// b = beta - mean*a.   grid: T*P blocks of 256.
// ---------------------------------------------------------------------------
__global__ __launch_bounds__(256) void bn_stats_kernel(
    const float* __restrict__ Y,      // [BT][P][M]
    const float* __restrict__ gamma,
    const float* __restrict__ beta,
    float* __restrict__ stats)        // [T][P][2]
{
    int o = blockIdx.x & 255;
    int t = blockIdx.x >> 8;
    int tid = threadIdx.x;
    float s1 = 0.0f, s2 = 0.0f;
    for (int b = 0; b < Bb; b++) {
        const float* row = Y + ((size_t)(b * Tt + t) * 256 + o) * Mm;
        for (int m = tid * 4; m < Mm; m += 1024) {
            float4 v = *(const float4*)&row[m];
            s1 += v.x + v.y + v.z + v.w;
            s2 += v.x * v.x + v.y * v.y + v.z * v.z + v.w * v.w;
        }
    }
    #pragma unroll
    for (int off = 32; off > 0; off >>= 1) {
        s1 += __shfl_down(s1, off);
        s2 += __shfl_down(s2, off);
    }
    __shared__ float r1[4], r2[4];
    int wv = tid >> 6;
    if ((tid & 63) == 0) { r1[wv] = s1; r2[wv] = s2; }
    __syncthreads();
    if (tid == 0) {
        float S1 = r1[0] + r1[1] + r1[2] + r1[3];
        float S2 = r2[0] + r2[1] + r2[2] + r2[3];
        const float inv = 1.0f / (float)(Bb * Mm);
        float mean = S1 * inv;
        float var  = S2 * inv - mean * mean;
        float a = gamma[o] * rsqrtf(var + EPS_BN);
        stats[(t * 256 + o) * 2 + 0] = a;
        stats[(t * 256 + o) * 2 + 1] = beta[o] - mean * a;
    }
}

// ---------------------------------------------------------------------------
// Kernel 6: final BN2 + relu apply -> d_out (after the xyz passthrough)
// ---------------------------------------------------------------------------
__global__ __launch_bounds__(256) void bn_apply_kernel(
    const float* __restrict__ Y,      // [BT][P][M]
    const float* __restrict__ stats,  // [T][P][2]
    float* __restrict__ out)
{
    size_t i4 = (size_t)blockIdx.x * 256 + threadIdx.x;
    size_t r = i4 >> 10;               // (bt*256 + o)
    int o  = (int)(r & 255);
    int bt = (int)(r >> 8);
    int t  = bt & (Tt - 1);
    float a = stats[(t * 256 + o) * 2 + 0];
    float b = stats[(t * 256 + o) * 2 + 1];
    float4 v = *(const float4*)&Y[i4 * 4];
    v.x = fmaxf(fmaf(a, v.x, b), 0.0f);
    v.y = fmaxf(fmaf(a, v.y, b), 0.0f);
    v.z = fmaxf(fmaf(a, v.z, b), 0.0f);
    v.w = fmaxf(fmaf(a, v.w, b), 0.0f);
    *(float4*)&out[i4 * 4] = v;
}

// ---------------------------------------------------------------------------
extern "C" void kernel_launch(void* const* d_in, const int* in_sizes, int n_in,
                              void* d_out, int out_size, void* d_ws, size_t ws_size,
                              hipStream_t stream)
{
    const float* xyzs   = (const float*)d_in[0];
    const float* oxyzs  = (const float*)d_in[1];
    const float* feats  = (const float*)d_in[2];
    const float* ofeats = (const float*)d_in[3];
    const float* W1     = (const float*)d_in[4];
    const float* gamma1 = (const float*)d_in[5];
    const float* beta1  = (const float*)d_in[6];
    const float* W2     = (const float*)d_in[7];
    const float* gamma2 = (const float*)d_in[8];
    const float* beta2  = (const float*)d_in[9];
    float* out = (float*)d_out;

    // workspace layout (bytes)
    char* ws = (char*)d_ws;
    int*   idx_ws = (int*)ws;                         // 393216 ints   (1.5 MB)
    float* w_ws   = (float*)(ws + 1572864);           // 393216 floats (1.5 MB)
    float* Wt1    = (float*)(ws + 3145728);           // 384*256
    float* Wt2    = (float*)(ws + 3538944);           // 256*256
    float* stats1 = (float*)(ws + 3801088);           // 4*256*2
    float* stats2 = (float*)(ws + 3809280);           // 4*256*2
    float* X      = (float*)(ws + 4194304);           // 32*384*4096 f (201.3 MB)
    float* Y1     = (float*)(ws + 4194304 + 201326592);  // 32*256*4096 f (134.2 MB)
    float* Y2     = X;  // X is dead after GEMM1; reuse its space for Y2

    // 1) passthrough output: original_xyzs  (B*T*M*3 = 393216 floats)
    hipMemcpyAsync(out, oxyzs, 393216 * sizeof(float),
                   hipMemcpyDeviceToDevice, stream);

    // 2) weight transposes
    transpose_w_kernel<<<(384 * 256 + 255) / 256, 256, 0, stream>>>(W1, Wt1, CTOT, 256);
    transpose_w_kernel<<<(256 * 256 + 255) / 256, 256, 0, stream>>>(W2, Wt2, P1, 256);

    // 3) three_nn
    three_nn_kernel<<<dim3(Mm / 256, BT), 256, 0, stream>>>(xyzs, oxyzs, idx_ws, w_ws);

    // 4) interpolate + concat -> X
    interp_concat_kernel<<<dim3(CTOT * (Mm / 256), BT), 256, 0, stream>>>(
        feats, ofeats, idx_ws, w_ws, X);

    // 5) GEMM1 (raw, pre-BN)
    gemm_kernel<CTOT, false><<<dim3(Mm / 128, 256 / 128, BT), 256, 0, stream>>>(
        Wt1, X, nullptr, Y1);

    // 6) BN1 stats
    bn_stats_kernel<<<Tt * 256, 256, 0, stream>>>(Y1, gamma1, beta1, stats1);

    // 7) GEMM2 with fused BN1+relu on the input
    gemm_kernel<P1, true><<<dim3(Mm / 128, 256 / 128, BT), 256, 0, stream>>>(
        Wt2, Y1, stats1, Y2);

    // 8) BN2 stats
    bn_stats_kernel<<<Tt * 256, 256, 0, stream>>>(Y2, gamma2, beta2, stats2);

    // 9) BN2 + relu apply -> out
    bn_apply_kernel<<<(BT * 256 * Mm / 4) / 256, 256, 0, stream>>>(
        Y2, stats2, out + 393216);
}

// Round 4
// 713.759 us; speedup vs baseline: 1.3625x; 1.3625x over previous
//
#include <hip/hip_runtime.h>
#include <hip/hip_bf16.h>

// Problem constants
#define Bb 8
#define Tt 4
#define Nn 1024
#define Mm 4096
#define BT 32         // B*T
#define CIN 256
#define CORIG 128
#define CTOT 384      // CIN + CORIG
#define P1 256
#define P2 256
#define EPS_D 1e-8f
#define EPS_BN 1e-5f

typedef __attribute__((ext_vector_type(4))) float f32x4;
typedef __attribute__((ext_vector_type(8))) short s16x8;

// ---- bf16 split helpers (RTNE; split exactness depends only on lo's rounding) ----
__device__ __forceinline__ unsigned short f2bf(float f) {
    unsigned int u = __float_as_uint(f);
    unsigned int r = (u + 0x7FFFu + ((u >> 16) & 1u)) >> 16;
    return (unsigned short)r;
}
__device__ __forceinline__ float bf2f(unsigned short b) {
    return __uint_as_float((unsigned int)b << 16);
}
__device__ __forceinline__ void split_bf16(float f, unsigned short& h, unsigned short& l) {
    h = f2bf(f);
    l = f2bf(f - bf2f(h));
}

// ---------------------------------------------------------------------------
// Kernel 1: split W[o][k] fp32 -> bf16 hi/lo pair (same [o][k] layout)
// ---------------------------------------------------------------------------
__global__ __launch_bounds__(256) void prep_w_kernel(
    const float* __restrict__ W, unsigned short* __restrict__ hi,
    unsigned short* __restrict__ lo, int total)
{
    int i = blockIdx.x * 256 + threadIdx.x;
    if (i < total) {
        unsigned short h, l;
        split_bf16(W[i], h, l);
        hi[i] = h; lo[i] = l;
    }
}

// ---------------------------------------------------------------------------
// Kernel 2: three_nn — per query point find 3 nearest (squared dist), weights
// ---------------------------------------------------------------------------
__global__ __launch_bounds__(256) void three_nn_kernel(
    const float* __restrict__ xyzs,   // [BT][N][3]
    const float* __restrict__ oxyzs,  // [BT][M][3]
    int*   __restrict__ idx_out,      // [BT][M][3]
    float* __restrict__ w_out)        // [BT][M][3]
{
    __shared__ float sx[Nn], sy[Nn], sz[Nn];
    int bt = blockIdx.y;
    const float* base = xyzs + (size_t)bt * Nn * 3;
    for (int i = threadIdx.x; i < Nn; i += 256) {
        sx[i] = base[i * 3 + 0];
        sy[i] = base[i * 3 + 1];
        sz[i] = base[i * 3 + 2];
    }
    __syncthreads();

    int m = blockIdx.x * 256 + threadIdx.x;
    size_t q = ((size_t)bt * Mm + m) * 3;
    float qx = oxyzs[q + 0], qy = oxyzs[q + 1], qz = oxyzs[q + 2];

    float d0 = 3.4e38f, d1 = 3.4e38f, d2v = 3.4e38f;
    int   i0 = 0, i1 = 0, i2 = 0;
    #pragma unroll 4
    for (int n = 0; n < Nn; n++) {
        float dx = qx - sx[n], dy = qy - sy[n], dz = qz - sz[n];
        float d = dx * dx + dy * dy + dz * dz;
        bool lt0 = d < d0, lt1 = d < d1, lt2 = d < d2v;
        i2  = lt1 ? i1 : (lt2 ? n : i2);
        d2v = lt1 ? d1 : (lt2 ? d : d2v);
        i1  = lt0 ? i0 : (lt1 ? n : i1);
        d1  = lt0 ? d0 : (lt1 ? d : d1);
        i0  = lt0 ? n : i0;
        d0  = lt0 ? d : d0;
    }
    float w0 = 1.0f / (d0 + EPS_D);
    float w1 = 1.0f / (d1 + EPS_D);
    float w2 = 1.0f / (d2v + EPS_D);
    float inv = 1.0f / (w0 + w1 + w2);
    idx_out[q + 0] = i0; idx_out[q + 1] = i1; idx_out[q + 2] = i2;
    w_out[q + 0] = w0 * inv; w_out[q + 1] = w1 * inv; w_out[q + 2] = w2 * inv;
}

// ---------------------------------------------------------------------------
// Kernel 3: interpolate + concat -> X [BT][384][M]  (fp32)
// ---------------------------------------------------------------------------
__global__ __launch_bounds__(256) void interp_concat_kernel(
    const float* __restrict__ feats,   // [BT][CIN][N]
    const float* __restrict__ ofeats,  // [BT][CORIG][M]
    const int*   __restrict__ idx,     // [BT][M][3]
    const float* __restrict__ w,       // [BT][M][3]
    float* __restrict__ X)             // [BT][CTOT][M]
{
    int bt = blockIdx.y;
    int c  = blockIdx.x >> 4;
    int m  = ((blockIdx.x & 15) << 8) | threadIdx.x;
    size_t xoff = ((size_t)bt * CTOT + c) * Mm + m;
    if (c < CIN) {
        size_t iw = ((size_t)bt * Mm + m) * 3;
        int   j0 = idx[iw + 0], j1 = idx[iw + 1], j2 = idx[iw + 2];
        float w0 = w[iw + 0],   w1 = w[iw + 1],   w2 = w[iw + 2];
        const float* frow = feats + ((size_t)bt * CIN + c) * Nn;
        X[xoff] = w0 * frow[j0] + w1 * frow[j1] + w2 * frow[j2];
    } else {
        X[xoff] = ofeats[((size_t)bt * CORIG + (c - CIN)) * Mm + m];
    }
}

// ---------------------------------------------------------------------------
// Kernel 4: split-bf16 MFMA GEMM.
//   Y[bt][o][m] = sum_c W[o][c] * f(X[bt][c][m]),  f = id or BN1+relu.
//   W pre-split to bf16 hi/lo [o][k]; X fp32, split during LDS staging.
//   3 MFMA products (hh, hl, lh) -> ~2^-17 rel err (fp32-grade).
//   Tile 128(o) x 128(m), BK=32, 4 waves each owning 64x64.
//   LDS rows padded to 40 elems (80 B) -> frag b128 reads are 2-way/free.
// grid: (Mm/128, 2, BT)
// ---------------------------------------------------------------------------
template <int KTOT, bool TRANSFORM>
__global__ __launch_bounds__(256) void mfma_gemm_kernel(
    const unsigned short* __restrict__ Whi,  // [256][KTOT] bf16 bits
    const unsigned short* __restrict__ Wlo,
    const float* __restrict__ Xg,            // [BT][KTOT][Mm]
    const float* __restrict__ stats,         // [T][KTOT][2] (a,b) or nullptr
    float* __restrict__ Y)                   // [BT][256][Mm]
{
    __shared__ unsigned short sAhi[128][40];
    __shared__ unsigned short sAlo[128][40];
    __shared__ unsigned short sBhi[128][40];
    __shared__ unsigned short sBlo[128][40];

    const int tid = threadIdx.x;
    const int bt = blockIdx.z, t = bt & (Tt - 1);
    const int m0 = blockIdx.x * 128, o0 = blockIdx.y * 128;

    // staging roles
    const int mo = tid & 127;    // tile row (o' for A, m' for B)
    const int kh = tid >> 7;     // k-half 0/1 (16 k each) — wave-uniform
    const float* Xb = Xg + (size_t)bt * KTOT * Mm + m0 + mo;

    // compute roles
    const int lane = tid & 63, wid = tid >> 6;
    const int wo = (wid >> 1) * 64, wm = (wid & 1) * 64;
    const int lr = lane & 15, kb = lane >> 4;

    f32x4 acc[4][4] = {};

    for (int k0 = 0; k0 < KTOT; k0 += 32) {
        // ---- stage A: copy bf16 hi/lo weight panel ----
        {
            const uint4* ph = (const uint4*)&Whi[(size_t)(o0 + mo) * KTOT + k0 + kh * 16];
            const uint4* pl = (const uint4*)&Wlo[(size_t)(o0 + mo) * KTOT + k0 + kh * 16];
            uint4 h0 = ph[0], h1 = ph[1];
            uint4 l0 = pl[0], l1 = pl[1];
            *(uint4*)&sAhi[mo][kh * 16]     = h0;
            *(uint4*)&sAhi[mo][kh * 16 + 8] = h1;
            *(uint4*)&sAlo[mo][kh * 16]     = l0;
            *(uint4*)&sAlo[mo][kh * 16 + 8] = l1;
        }
        // ---- stage B: fp32 -> bf16 hi/lo, transposed [m][k] ----
        {
            float v[16];
            #pragma unroll
            for (int kk = 0; kk < 16; kk++)
                v[kk] = Xb[(size_t)(k0 + kh * 16 + kk) * Mm];
            if (TRANSFORM) {
                #pragma unroll
                for (int kk = 0; kk < 16; kk++) {
                    int k = k0 + kh * 16 + kk;   // wave-uniform
                    float a = stats[(t * KTOT + k) * 2 + 0];
                    float b = stats[(t * KTOT + k) * 2 + 1];
                    v[kk] = fmaxf(fmaf(a, v[kk], b), 0.0f);
                }
            }
            s16x8 H0, H1, L0, L1;
            #pragma unroll
            for (int kk = 0; kk < 8; kk++) {
                unsigned short h, l;
                split_bf16(v[kk], h, l);
                H0[kk] = (short)h; L0[kk] = (short)l;
                split_bf16(v[kk + 8], h, l);
                H1[kk] = (short)h; L1[kk] = (short)l;
            }
            *(s16x8*)&sBhi[mo][kh * 16]     = H0;
            *(s16x8*)&sBhi[mo][kh * 16 + 8] = H1;
            *(s16x8*)&sBlo[mo][kh * 16]     = L0;
            *(s16x8*)&sBlo[mo][kh * 16 + 8] = L1;
        }
        __syncthreads();

        // ---- compute: 16 frag reads + 48 MFMA ----
        s16x8 ah[4], al[4], bh[4], bl[4];
        #pragma unroll
        for (int f = 0; f < 4; f++) {
            ah[f] = *(const s16x8*)&sAhi[wo + f * 16 + lr][kb * 8];
            al[f] = *(const s16x8*)&sAlo[wo + f * 16 + lr][kb * 8];
            bh[f] = *(const s16x8*)&sBhi[wm + f * 16 + lr][kb * 8];
            bl[f] = *(const s16x8*)&sBlo[wm + f * 16 + lr][kb * 8];
        }
        #pragma unroll
        for (int fo = 0; fo < 4; fo++) {
            #pragma unroll
            for (int fn = 0; fn < 4; fn++) {
                acc[fo][fn] = __builtin_amdgcn_mfma_f32_16x16x32_bf16(ah[fo], bh[fn], acc[fo][fn], 0, 0, 0);
                acc[fo][fn] = __builtin_amdgcn_mfma_f32_16x16x32_bf16(ah[fo], bl[fn], acc[fo][fn], 0, 0, 0);
                acc[fo][fn] = __builtin_amdgcn_mfma_f32_16x16x32_bf16(al[fo], bh[fn], acc[fo][fn], 0, 0, 0);
            }
        }
        __syncthreads();
    }

    // ---- epilogue: D[i=4*kb+r][j=lr] per frag ----
    float* Yb = Y + (size_t)bt * 256 * Mm;
    #pragma unroll
    for (int fo = 0; fo < 4; fo++) {
        int obase = o0 + wo + fo * 16 + kb * 4;
        #pragma unroll
        for (int r = 0; r < 4; r++) {
            float* row = &Yb[(size_t)(obase + r) * Mm + m0 + wm + lr];
            #pragma unroll
            for (int fn = 0; fn < 4; fn++)
                row[fn * 16] = acc[fo][fn][r];
        }
    }
}

// ---------------------------------------------------------------------------
// Kernel 5: BN stats per (t,o) over (B, M): a = gamma*rsqrt(var+eps),
// b = beta - mean*a.
// ---------------------------------------------------------------------------
__global__ __launch_bounds__(256) void bn_stats_kernel(
    const float* __restrict__ Y,      // [BT][P][M]
    const float* __restrict__ gamma,
    const float* __restrict__ beta,
    float* __restrict__ stats)        // [T][P][2]
{
    int o = blockIdx.x & 255;
    int t = blockIdx.x >> 8;
    int tid = threadIdx.x;
    float s1 = 0.0f, s2 = 0.0f;
    for (int b = 0; b < Bb; b++) {
        const float* row = Y + ((size_t)(b * Tt + t) * 256 + o) * Mm;
        for (int m = tid * 4; m < Mm; m += 1024) {
            float4 v = *(const float4*)&row[m];
            s1 += v.x + v.y + v.z + v.w;
            s2 += v.x * v.x + v.y * v.y + v.z * v.z + v.w * v.w;
        }
    }
    #pragma unroll
    for (int off = 32; off > 0; off >>= 1) {
        s1 += __shfl_down(s1, off);
        s2 += __shfl_down(s2, off);
    }
    __shared__ float r1[4], r2[4];
    int wv = tid >> 6;
    if ((tid & 63) == 0) { r1[wv] = s1; r2[wv] = s2; }
    __syncthreads();
    if (tid == 0) {
        float S1 = r1[0] + r1[1] + r1[2] + r1[3];
        float S2 = r2[0] + r2[1] + r2[2] + r2[3];
        const float inv = 1.0f / (float)(Bb * Mm);
        float mean = S1 * inv;
        float var  = S2 * inv - mean * mean;
        float a = gamma[o] * rsqrtf(var + EPS_BN);
        stats[(t * 256 + o) * 2 + 0] = a;
        stats[(t * 256 + o) * 2 + 1] = beta[o] - mean * a;
    }
}

// ---------------------------------------------------------------------------
// Kernel 6: final BN2 + relu apply -> d_out
// ---------------------------------------------------------------------------
__global__ __launch_bounds__(256) void bn_apply_kernel(
    const float* __restrict__ Y,      // [BT][P][M]
    const float* __restrict__ stats,  // [T][P][2]
    float* __restrict__ out)
{
    size_t i4 = (size_t)blockIdx.x * 256 + threadIdx.x;
    size_t r = i4 >> 10;               // (bt*256 + o)
    int o  = (int)(r & 255);
    int bt = (int)(r >> 8);
    int t  = bt & (Tt - 1);
    float a = stats[(t * 256 + o) * 2 + 0];
    float b = stats[(t * 256 + o) * 2 + 1];
    float4 v = *(const float4*)&Y[i4 * 4];
    v.x = fmaxf(fmaf(a, v.x, b), 0.0f);
    v.y = fmaxf(fmaf(a, v.y, b), 0.0f);
    v.z = fmaxf(fmaf(a, v.z, b), 0.0f);
    v.w = fmaxf(fmaf(a, v.w, b), 0.0f);
    *(float4*)&out[i4 * 4] = v;
}

// ---------------------------------------------------------------------------
extern "C" void kernel_launch(void* const* d_in, const int* in_sizes, int n_in,
                              void* d_out, int out_size, void* d_ws, size_t ws_size,
                              hipStream_t stream)
{
    const float* xyzs   = (const float*)d_in[0];
    const float* oxyzs  = (const float*)d_in[1];
    const float* feats  = (const float*)d_in[2];
    const float* ofeats = (const float*)d_in[3];
    const float* W1     = (const float*)d_in[4];
    const float* gamma1 = (const float*)d_in[5];
    const float* beta1  = (const float*)d_in[6];
    const float* W2     = (const float*)d_in[7];
    const float* gamma2 = (const float*)d_in[8];
    const float* beta2  = (const float*)d_in[9];
    float* out = (float*)d_out;

    // workspace layout (bytes)
    char* ws = (char*)d_ws;
    int*            idx_ws = (int*)ws;                          // 1,572,864 B
    float*          w_ws   = (float*)(ws + 1572864);            // 1,572,864 B
    unsigned short* Whi1   = (unsigned short*)(ws + 3145728);   // 196,608 B
    unsigned short* Wlo1   = (unsigned short*)(ws + 3342336);   // 196,608 B
    unsigned short* Whi2   = (unsigned short*)(ws + 3538944);   // 131,072 B
    unsigned short* Wlo2   = (unsigned short*)(ws + 3670016);   // 131,072 B
    float*          stats1 = (float*)(ws + 3801088);            // 8,192 B
    float*          stats2 = (float*)(ws + 3809280);            // 8,192 B
    float*          X      = (float*)(ws + 4194304);            // 201,326,592 B
    float*          Y1     = (float*)(ws + 4194304 + 201326592);// 134,217,728 B
    float*          Y2     = X;   // X dead after GEMM1

    // 1) passthrough output: original_xyzs
    hipMemcpyAsync(out, oxyzs, 393216 * sizeof(float),
                   hipMemcpyDeviceToDevice, stream);

    // 2) weight hi/lo splits
    prep_w_kernel<<<(P1 * CTOT + 255) / 256, 256, 0, stream>>>(W1, Whi1, Wlo1, P1 * CTOT);
    prep_w_kernel<<<(P2 * P1 + 255) / 256, 256, 0, stream>>>(W2, Whi2, Wlo2, P2 * P1);

    // 3) three_nn
    three_nn_kernel<<<dim3(Mm / 256, BT), 256, 0, stream>>>(xyzs, oxyzs, idx_ws, w_ws);

    // 4) interpolate + concat -> X
    interp_concat_kernel<<<dim3(CTOT * (Mm / 256), BT), 256, 0, stream>>>(
        feats, ofeats, idx_ws, w_ws, X);

    // 5) GEMM1 (split-bf16 MFMA)
    mfma_gemm_kernel<CTOT, false><<<dim3(Mm / 128, 2, BT), 256, 0, stream>>>(
        Whi1, Wlo1, X, nullptr, Y1);

    // 6) BN1 stats
    bn_stats_kernel<<<Tt * 256, 256, 0, stream>>>(Y1, gamma1, beta1, stats1);

    // 7) GEMM2 with fused BN1+relu on the input
    mfma_gemm_kernel<P1, true><<<dim3(Mm / 128, 2, BT), 256, 0, stream>>>(
        Whi2, Wlo2, Y1, stats1, Y2);

    // 8) BN2 stats
    bn_stats_kernel<<<Tt * 256, 256, 0, stream>>>(Y2, gamma2, beta2, stats2);

    // 9) BN2 + relu apply -> out
    bn_apply_kernel<<<(BT * 256 * Mm / 4) / 256, 256, 0, stream>>>(
        Y2, stats2, out + 393216);
}

// Round 5
// 634.399 us; speedup vs baseline: 1.5329x; 1.1251x over previous
//
#include <hip/hip_runtime.h>
#include <hip/hip_bf16.h>

// Problem constants
#define Bb 8
#define Tt 4
#define Nn 1024
#define Mm 4096
#define BT 32         // B*T
#define CIN 256
#define CORIG 128
#define CTOT 384      // CIN + CORIG
#define P1 256
#define P2 256
#define EPS_D 1e-8f
#define EPS_BN 1e-5f

typedef __attribute__((ext_vector_type(4))) float f32x4;
typedef __attribute__((ext_vector_type(8))) short s16x8;

// ---- bf16 split helpers (RTNE; split exactness depends only on lo's rounding) ----
__device__ __forceinline__ unsigned short f2bf(float f) {
    unsigned int u = __float_as_uint(f);
    unsigned int r = (u + 0x7FFFu + ((u >> 16) & 1u)) >> 16;
    return (unsigned short)r;
}
__device__ __forceinline__ float bf2f(unsigned short b) {
    return __uint_as_float((unsigned int)b << 16);
}
__device__ __forceinline__ void split_bf16(float f, unsigned short& h, unsigned short& l) {
    h = f2bf(f);
    l = f2bf(f - bf2f(h));
}

// ---------------------------------------------------------------------------
// Kernel 1: split W[o][k] fp32 -> bf16 hi/lo pair (same [o][k] layout)
// ---------------------------------------------------------------------------
__global__ __launch_bounds__(256) void prep_w_kernel(
    const float* __restrict__ W, unsigned short* __restrict__ hi,
    unsigned short* __restrict__ lo, int total)
{
    int i = blockIdx.x * 256 + threadIdx.x;
    if (i < total) {
        unsigned short h, l;
        split_bf16(W[i], h, l);
        hi[i] = h; lo[i] = l;
    }
}

// ---------------------------------------------------------------------------
// Kernel 2: three_nn — per query point find 3 nearest (squared dist), weights
// ---------------------------------------------------------------------------
__global__ __launch_bounds__(256) void three_nn_kernel(
    const float* __restrict__ xyzs,   // [BT][N][3]
    const float* __restrict__ oxyzs,  // [BT][M][3]
    int*   __restrict__ idx_out,      // [BT][M][3]
    float* __restrict__ w_out)        // [BT][M][3]
{
    __shared__ float sx[Nn], sy[Nn], sz[Nn];
    int bt = blockIdx.y;
    const float* base = xyzs + (size_t)bt * Nn * 3;
    for (int i = threadIdx.x; i < Nn; i += 256) {
        sx[i] = base[i * 3 + 0];
        sy[i] = base[i * 3 + 1];
        sz[i] = base[i * 3 + 2];
    }
    __syncthreads();

    int m = blockIdx.x * 256 + threadIdx.x;
    size_t q = ((size_t)bt * Mm + m) * 3;
    float qx = oxyzs[q + 0], qy = oxyzs[q + 1], qz = oxyzs[q + 2];

    float d0 = 3.4e38f, d1 = 3.4e38f, d2v = 3.4e38f;
    int   i0 = 0, i1 = 0, i2 = 0;
    #pragma unroll 4
    for (int n = 0; n < Nn; n++) {
        float dx = qx - sx[n], dy = qy - sy[n], dz = qz - sz[n];
        float d = dx * dx + dy * dy + dz * dz;
        bool lt0 = d < d0, lt1 = d < d1, lt2 = d < d2v;
        i2  = lt1 ? i1 : (lt2 ? n : i2);
        d2v = lt1 ? d1 : (lt2 ? d : d2v);
        i1  = lt0 ? i0 : (lt1 ? n : i1);
        d1  = lt0 ? d0 : (lt1 ? d : d1);
        i0  = lt0 ? n : i0;
        d0  = lt0 ? d : d0;
    }
    float w0 = 1.0f / (d0 + EPS_D);
    float w1 = 1.0f / (d1 + EPS_D);
    float w2 = 1.0f / (d2v + EPS_D);
    float inv = 1.0f / (w0 + w1 + w2);
    idx_out[q + 0] = i0; idx_out[q + 1] = i1; idx_out[q + 2] = i2;
    w_out[q + 0] = w0 * inv; w_out[q + 1] = w1 * inv; w_out[q + 2] = w2 * inv;
}

// ---------------------------------------------------------------------------
// Kernel 3: transpose feats [BT][256][1024] -> featsT [BT][1024][256]
// 64x64 tiles, LDS pad 65. grid (16, 4, BT)
// ---------------------------------------------------------------------------
__global__ __launch_bounds__(256) void transpose_feats_kernel(
    const float* __restrict__ feats, float* __restrict__ featsT)
{
    __shared__ float tile[64][65];
    int bt = blockIdx.z;
    int n0 = blockIdx.x * 64;
    int c0 = blockIdx.y * 64;
    int tx = threadIdx.x & 63;
    int ty = threadIdx.x >> 6;
    const float* src = feats + ((size_t)bt * CIN + c0) * Nn + n0;
    #pragma unroll
    for (int r = 0; r < 16; r++) {
        int c = ty + r * 4;
        tile[c][tx] = src[(size_t)c * Nn + tx];
    }
    __syncthreads();
    float* dst = featsT + ((size_t)bt * Nn + n0) * CIN + c0;
    #pragma unroll
    for (int r = 0; r < 16; r++) {
        int n = ty + r * 4;
        dst[(size_t)n * CIN + tx] = tile[tx][n];
    }
}

// ---------------------------------------------------------------------------
// Kernel 4: interpolate -> Xi [BT][256][M]
// The gather index j(m) is c-invariant: flip axes so lanes run over c and the
// "gather" becomes 3 coalesced row reads of featsT[j][0:256]. Output goes
// through a padded LDS tile to restore [c][m]-major coalesced writes.
// grid (M/32, BT), block 256 (thread = channel c)
// ---------------------------------------------------------------------------
__global__ __launch_bounds__(256) void interp_kernel(
    const float* __restrict__ featsT,  // [BT][1024][256]
    const int*   __restrict__ idx,     // [BT][M][3]
    const float* __restrict__ w,       // [BT][M][3]
    float* __restrict__ Xi)            // [BT][256][M]
{
    __shared__ float sX[256][33];
    __shared__ int   sidx[96];
    __shared__ float swgt[96];
    int bt = blockIdx.y;
    int m0 = blockIdx.x * 32;
    int tid = threadIdx.x;
    size_t base = ((size_t)bt * Mm + m0) * 3;
    if (tid < 96)       sidx[tid]      = idx[base + tid];
    else if (tid < 192) swgt[tid - 96] = w[base + tid - 96];
    __syncthreads();

    const float* fb = featsT + (size_t)bt * Nn * CIN + tid;   // c = tid
    #pragma unroll 4
    for (int mm = 0; mm < 32; mm++) {
        int   j0 = sidx[mm * 3 + 0], j1 = sidx[mm * 3 + 1], j2 = sidx[mm * 3 + 2];
        float w0 = swgt[mm * 3 + 0], w1 = swgt[mm * 3 + 1], w2 = swgt[mm * 3 + 2];
        sX[tid][mm] = w0 * fb[(size_t)j0 * CIN]
                    + w1 * fb[(size_t)j1 * CIN]
                    + w2 * fb[(size_t)j2 * CIN];
    }
    __syncthreads();

    float* xb = Xi + (size_t)bt * CIN * Mm + m0;
    #pragma unroll
    for (int i = 0; i < 8; i++) {
        int row = i * 32 + (tid >> 3);
        int col = (tid & 7) * 4;
        float4 v = make_float4(sX[row][col], sX[row][col + 1],
                               sX[row][col + 2], sX[row][col + 3]);
        *(float4*)&xb[(size_t)row * Mm + col] = v;
    }
}

// ---------------------------------------------------------------------------
// Kernel 5: split-bf16 MFMA GEMM.
//   Y[bt][o][m] = sum_c W[o][c] * f(src[c][m]),  f = id or BN1+relu.
//   CONCAT: k<CIN reads Xi, k>=CIN reads ofeats directly (zero-copy concat).
//   3 MFMA products (hh, hl, lh) -> ~2^-17 rel err.
//   Tile 128(o) x 128(m), BK=32, 4 waves each owning 64x64.
// grid: (Mm/128, 2, BT)
// ---------------------------------------------------------------------------
template <int KTOT, bool TRANSFORM, bool CONCAT>
__global__ __launch_bounds__(256) void mfma_gemm_kernel(
    const unsigned short* __restrict__ Whi,  // [256][KTOT] bf16 bits
    const unsigned short* __restrict__ Wlo,
    const float* __restrict__ Xg,            // [BT][CIN or KTOT][Mm]
    const float* __restrict__ OF,            // [BT][CORIG][Mm] or nullptr
    const float* __restrict__ stats,         // [T][KTOT][2] (a,b) or nullptr
    float* __restrict__ Y)                   // [BT][256][Mm]
{
    __shared__ unsigned short sAhi[128][40];
    __shared__ unsigned short sAlo[128][40];
    __shared__ unsigned short sBhi[128][40];
    __shared__ unsigned short sBlo[128][40];

    const int tid = threadIdx.x;
    const int bt = blockIdx.z, t = bt & (Tt - 1);
    const int m0 = blockIdx.x * 128, o0 = blockIdx.y * 128;

    // staging roles
    const int mo = tid & 127;    // tile row (o' for A, m' for B)
    const int kh = tid >> 7;     // k-half 0/1 (16 k each) — wave-uniform
    const float* Xb  = Xg + (size_t)bt * (CONCAT ? CIN : KTOT) * Mm + m0 + mo;
    const float* OFb = CONCAT ? (OF + (size_t)bt * CORIG * Mm + m0 + mo) : nullptr;

    // compute roles
    const int lane = tid & 63, wid = tid >> 6;
    const int wo = (wid >> 1) * 64, wm = (wid & 1) * 64;
    const int lr = lane & 15, kb = lane >> 4;

    f32x4 acc[4][4] = {};

    for (int k0 = 0; k0 < KTOT; k0 += 32) {
        // ---- stage A: copy bf16 hi/lo weight panel ----
        {
            const uint4* ph = (const uint4*)&Whi[(size_t)(o0 + mo) * KTOT + k0 + kh * 16];
            const uint4* pl = (const uint4*)&Wlo[(size_t)(o0 + mo) * KTOT + k0 + kh * 16];
            uint4 h0 = ph[0], h1 = ph[1];
            uint4 l0 = pl[0], l1 = pl[1];
            *(uint4*)&sAhi[mo][kh * 16]     = h0;
            *(uint4*)&sAhi[mo][kh * 16 + 8] = h1;
            *(uint4*)&sAlo[mo][kh * 16]     = l0;
            *(uint4*)&sAlo[mo][kh * 16 + 8] = l1;
        }
        // ---- stage B: fp32 -> bf16 hi/lo, transposed [m][k] ----
        {
            const int kg = k0 + kh * 16;     // wave-uniform; 16-k group never straddles CIN
            const float* bsrc = (CONCAT && kg >= CIN)
                              ? (OFb + (size_t)(kg - CIN) * Mm)
                              : (Xb + (size_t)kg * Mm);
            float v[16];
            #pragma unroll
            for (int kk = 0; kk < 16; kk++)
                v[kk] = bsrc[(size_t)kk * Mm];
            if (TRANSFORM) {
                #pragma unroll
                for (int kk = 0; kk < 16; kk++) {
                    int k = kg + kk;   // wave-uniform
                    float a = stats[(t * KTOT + k) * 2 + 0];
                    float b = stats[(t * KTOT + k) * 2 + 1];
                    v[kk] = fmaxf(fmaf(a, v[kk], b), 0.0f);
                }
            }
            s16x8 H0, H1, L0, L1;
            #pragma unroll
            for (int kk = 0; kk < 8; kk++) {
                unsigned short h, l;
                split_bf16(v[kk], h, l);
                H0[kk] = (short)h; L0[kk] = (short)l;
                split_bf16(v[kk + 8], h, l);
                H1[kk] = (short)h; L1[kk] = (short)l;
            }
            *(s16x8*)&sBhi[mo][kh * 16]     = H0;
            *(s16x8*)&sBhi[mo][kh * 16 + 8] = H1;
            *(s16x8*)&sBlo[mo][kh * 16]     = L0;
            *(s16x8*)&sBlo[mo][kh * 16 + 8] = L1;
        }
        __syncthreads();

        // ---- compute: 16 frag reads + 48 MFMA ----
        s16x8 ah[4], al[4], bh[4], bl[4];
        #pragma unroll
        for (int f = 0; f < 4; f++) {
            ah[f] = *(const s16x8*)&sAhi[wo + f * 16 + lr][kb * 8];
            al[f] = *(const s16x8*)&sAlo[wo + f * 16 + lr][kb * 8];
            bh[f] = *(const s16x8*)&sBhi[wm + f * 16 + lr][kb * 8];
            bl[f] = *(const s16x8*)&sBlo[wm + f * 16 + lr][kb * 8];
        }
        #pragma unroll
        for (int fo = 0; fo < 4; fo++) {
            #pragma unroll
            for (int fn = 0; fn < 4; fn++) {
                acc[fo][fn] = __builtin_amdgcn_mfma_f32_16x16x32_bf16(ah[fo], bh[fn], acc[fo][fn], 0, 0, 0);
                acc[fo][fn] = __builtin_amdgcn_mfma_f32_16x16x32_bf16(ah[fo], bl[fn], acc[fo][fn], 0, 0, 0);
                acc[fo][fn] = __builtin_amdgcn_mfma_f32_16x16x32_bf16(al[fo], bh[fn], acc[fo][fn], 0, 0, 0);
            }
        }
        __syncthreads();
    }

    // ---- epilogue: D[i=4*kb+r][j=lr] per frag ----
    float* Yb = Y + (size_t)bt * 256 * Mm;
    #pragma unroll
    for (int fo = 0; fo < 4; fo++) {
        int obase = o0 + wo + fo * 16 + kb * 4;
        #pragma unroll
        for (int r = 0; r < 4; r++) {
            float* row = &Yb[(size_t)(obase + r) * Mm + m0 + wm + lr];
            #pragma unroll
            for (int fn = 0; fn < 4; fn++)
                row[fn * 16] = acc[fo][fn][r];
        }
    }
}

// ---------------------------------------------------------------------------
// Kernel 6: BN stats per (t,o) over (B, M): a = gamma*rsqrt(var+eps),
// b = beta - mean*a.
// ---------------------------------------------------------------------------
__global__ __launch_bounds__(256) void bn_stats_kernel(
    const float* __restrict__ Y,      // [BT][P][M]
    const float* __restrict__ gamma,
    const float* __restrict__ beta,
    float* __restrict__ stats)        // [T][P][2]
{
    int o = blockIdx.x & 255;
    int t = blockIdx.x >> 8;
    int tid = threadIdx.x;
    float s1 = 0.0f, s2 = 0.0f;
    for (int b = 0; b < Bb; b++) {
        const float* row = Y + ((size_t)(b * Tt + t) * 256 + o) * Mm;
        for (int m = tid * 4; m < Mm; m += 1024) {
            float4 v = *(const float4*)&row[m];
            s1 += v.x + v.y + v.z + v.w;
            s2 += v.x * v.x + v.y * v.y + v.z * v.z + v.w * v.w;
        }
    }
    #pragma unroll
    for (int off = 32; off > 0; off >>= 1) {
        s1 += __shfl_down(s1, off);
        s2 += __shfl_down(s2, off);
    }
    __shared__ float r1[4], r2[4];
    int wv = tid >> 6;
    if ((tid & 63) == 0) { r1[wv] = s1; r2[wv] = s2; }
    __syncthreads();
    if (tid == 0) {
        float S1 = r1[0] + r1[1] + r1[2] + r1[3];
        float S2 = r2[0] + r2[1] + r2[2] + r2[3];
        const float inv = 1.0f / (float)(Bb * Mm);
        float mean = S1 * inv;
        float var  = S2 * inv - mean * mean;
        float a = gamma[o] * rsqrtf(var + EPS_BN);
        stats[(t * 256 + o) * 2 + 0] = a;
        stats[(t * 256 + o) * 2 + 1] = beta[o] - mean * a;
    }
}

// ---------------------------------------------------------------------------
// Kernel 7: final BN2 + relu apply -> d_out
// ---------------------------------------------------------------------------
__global__ __launch_bounds__(256) void bn_apply_kernel(
    const float* __restrict__ Y,      // [BT][P][M]
    const float* __restrict__ stats,  // [T][P][2]
    float* __restrict__ out)
{
    size_t i4 = (size_t)blockIdx.x * 256 + threadIdx.x;
    size_t r = i4 >> 10;               // (bt*256 + o)
    int o  = (int)(r & 255);
    int bt = (int)(r >> 8);
    int t  = bt & (Tt - 1);
    float a = stats[(t * 256 + o) * 2 + 0];
    float b = stats[(t * 256 + o) * 2 + 1];
    float4 v = *(const float4*)&Y[i4 * 4];
    v.x = fmaxf(fmaf(a, v.x, b), 0.0f);
    v.y = fmaxf(fmaf(a, v.y, b), 0.0f);
    v.z = fmaxf(fmaf(a, v.z, b), 0.0f);
    v.w = fmaxf(fmaf(a, v.w, b), 0.0f);
    *(float4*)&out[i4 * 4] = v;
}

// ---------------------------------------------------------------------------
extern "C" void kernel_launch(void* const* d_in, const int* in_sizes, int n_in,
                              void* d_out, int out_size, void* d_ws, size_t ws_size,
                              hipStream_t stream)
{
    const float* xyzs   = (const float*)d_in[0];
    const float* oxyzs  = (const float*)d_in[1];
    const float* feats  = (const float*)d_in[2];
    const float* ofeats = (const float*)d_in[3];
    const float* W1     = (const float*)d_in[4];
    const float* gamma1 = (const float*)d_in[5];
    const float* beta1  = (const float*)d_in[6];
    const float* W2     = (const float*)d_in[7];
    const float* gamma2 = (const float*)d_in[8];
    const float* beta2  = (const float*)d_in[9];
    float* out = (float*)d_out;

    // workspace layout (bytes)
    char* ws = (char*)d_ws;
    int*            idx_ws = (int*)ws;                          // 1,572,864 B
    float*          w_ws   = (float*)(ws + 1572864);            // 1,572,864 B
    unsigned short* Whi1   = (unsigned short*)(ws + 3145728);   // 196,608 B
    unsigned short* Wlo1   = (unsigned short*)(ws + 3342336);   // 196,608 B
    unsigned short* Whi2   = (unsigned short*)(ws + 3538944);   // 131,072 B
    unsigned short* Wlo2   = (unsigned short*)(ws + 3670016);   // 131,072 B
    float*          stats1 = (float*)(ws + 3801088);            // 8,192 B
    float*          stats2 = (float*)(ws + 3809280);            // 8,192 B
    float*          featsT = (float*)(ws + 4194304);            // 33,554,432 B
    float*          Xi     = (float*)(ws + 37748736);           // 134,217,728 B
    float*          Y1     = (float*)(ws + 171966464);          // 134,217,728 B
    float*          Y2     = Xi;   // Xi dead after GEMM1

    // 1) passthrough output: original_xyzs
    hipMemcpyAsync(out, oxyzs, 393216 * sizeof(float),
                   hipMemcpyDeviceToDevice, stream);

    // 2) weight hi/lo splits
    prep_w_kernel<<<(P1 * CTOT + 255) / 256, 256, 0, stream>>>(W1, Whi1, Wlo1, P1 * CTOT);
    prep_w_kernel<<<(P2 * P1 + 255) / 256, 256, 0, stream>>>(W2, Whi2, Wlo2, P2 * P1);

    // 3) three_nn
    three_nn_kernel<<<dim3(Mm / 256, BT), 256, 0, stream>>>(xyzs, oxyzs, idx_ws, w_ws);

    // 4) feats transpose + coalesced interp
    transpose_feats_kernel<<<dim3(Nn / 64, CIN / 64, BT), 256, 0, stream>>>(feats, featsT);
    interp_kernel<<<dim3(Mm / 32, BT), 256, 0, stream>>>(featsT, idx_ws, w_ws, Xi);

    // 5) GEMM1 (split-bf16 MFMA, zero-copy concat of ofeats)
    mfma_gemm_kernel<CTOT, false, true><<<dim3(Mm / 128, 2, BT), 256, 0, stream>>>(
        Whi1, Wlo1, Xi, ofeats, nullptr, Y1);

    // 6) BN1 stats
    bn_stats_kernel<<<Tt * 256, 256, 0, stream>>>(Y1, gamma1, beta1, stats1);

    // 7) GEMM2 with fused BN1+relu on the input
    mfma_gemm_kernel<P1, true, false><<<dim3(Mm / 128, 2, BT), 256, 0, stream>>>(
        Whi2, Wlo2, Y1, nullptr, stats1, Y2);

    // 8) BN2 stats
    bn_stats_kernel<<<Tt * 256, 256, 0, stream>>>(Y2, gamma2, beta2, stats2);

    // 9) BN2 + relu apply -> out
    bn_apply_kernel<<<(BT * 256 * Mm / 4) / 256, 256, 0, stream>>>(
        Y2, stats2, out + 393216);
}